// Round 2
// baseline (371.569 us; speedup 1.0000x reference)
//
#include <hip/hip_runtime.h>
#include <math.h>

#define D 128
#define NE 8192
#define NT 8192
#define KEXT 384       // [Ah|Ah|Al] x [Bh|Bl|Bh] -> Ah.Bh + Ah.Bl + Al.Bh
#define NKB (KEXT / 32)  // 12 k-blocks of 32
#define SB 16          // samples per projection block (= one 16-row fragment tile)

typedef __bf16 bf16x8 __attribute__((ext_vector_type(8)));
typedef float f32x4 __attribute__((ext_vector_type(4)));

__device__ __forceinline__ unsigned short f32_to_bf16(float f) {
  unsigned int u = __float_as_uint(f);
  u += 0x7FFFu + ((u >> 16) & 1u);   // RNE
  return (unsigned short)(u >> 16);
}
__device__ __forceinline__ float bf16_to_f32(unsigned short h) {
  return __uint_as_float(((unsigned int)h) << 16);
}

// ---------------------------------------------------------------- prep: M = W @ U_k
__global__ __launch_bounds__(128) void prep_M(const float* __restrict__ W,
                                              const float* __restrict__ U,
                                              float* __restrict__ M) {
  const int d = blockIdx.x;
  const int k = threadIdx.x;
  const float* Wr = W + d * D;
  float acc = 0.f;
#pragma unroll 8
  for (int c = 0; c < D; ++c) acc += Wr[c] * U[c * D + k];
  M[d * D + k] = acc;  // y[k] = sum_d M[d][k] v[d]
}

// ---------------------------------------------------------------- projection + scores
// Emits A/B in MFMA-fragment-packed layout:
//   chunk index (uint4 units) = rowblk*768 + kb*64 + koct*16 + s
//   lane l of the GEMM reads chunk (koct= l>>4, s= l&15) of (rowblk, kb).
__global__ __launch_bounds__(128) void project_kernel(
    const float* __restrict__ Xe, const float* __restrict__ Xt,
    const float* __restrict__ miu, const float* __restrict__ M,
    const float* __restrict__ Qh, const float* __restrict__ lam,
    unsigned short* __restrict__ Aext, unsigned short* __restrict__ Bext,
    float* __restrict__ s1, float* __restrict__ s2) {
  const int t = threadIdx.x;          // t = dim d (load) / output k (matvecs)
  const int mode = blockIdx.y;        // 0 = enroll, 1 = test
  const int R = blockIdx.x;           // rowblk
  const int n0 = R * SB;
  const float* X = mode ? Xt : Xe;
  unsigned short* Ext = mode ? Bext : Aext;
  float* sc = mode ? s2 : s1;

  __shared__ __align__(16) float V[D][20];
  __shared__ __align__(16) float Y[D][20];
  __shared__ float rn[SB];
  __shared__ __align__(16) unsigned short H[SB][136];  // pad 136: conflict-free col reads
  __shared__ __align__(16) unsigned short L[SB][136];

  // load + center
  const float mu = miu[t];
#pragma unroll
  for (int i = 0; i < SB; ++i)
    V[t][i] = X[(size_t)(n0 + i) * D + t] - mu;
  __syncthreads();

  // per-sample inverse norm
  if (t < SB) {
    float s = 0.f;
#pragma unroll 8
    for (int d = 0; d < D; ++d) { float v = V[d][t]; s += v * v; }
    rn[t] = 1.0f / (sqrtf(s) + 1e-8f);
  }
  __syncthreads();

  // matvec1: y[k=t][s] = sum_d M[d][k] * V[d][s]
  float y[SB];
#pragma unroll
  for (int s = 0; s < SB; ++s) y[s] = 0.f;
  {
    const float* Mc = M + t;
#pragma unroll 4
    for (int d = 0; d < D; ++d) {
      float m = Mc[d * D];
#pragma unroll
      for (int s4 = 0; s4 < SB / 4; ++s4) {
        float4 v = *(const float4*)&V[d][s4 * 4];
        y[s4 * 4 + 0] += m * v.x;
        y[s4 * 4 + 1] += m * v.y;
        y[s4 * 4 + 2] += m * v.z;
        y[s4 * 4 + 3] += m * v.w;
      }
    }
  }
#pragma unroll
  for (int s = 0; s < SB; ++s) y[s] *= rn[s];

#pragma unroll
  for (int s4 = 0; s4 < SB / 4; ++s4) {
    float4 v;
    v.x = y[s4 * 4 + 0]; v.y = y[s4 * 4 + 1];
    v.z = y[s4 * 4 + 2]; v.w = y[s4 * 4 + 3];
    *(float4*)&Y[t][s4 * 4] = v;
  }
  __syncthreads();

  // matvec2: z[k=t][s] = sum_d Qh[d][k] * Y[d][s]  (Q_hat symmetric)
  float z[SB];
#pragma unroll
  for (int s = 0; s < SB; ++s) z[s] = 0.f;
  {
    const float* Qc = Qh + t;
#pragma unroll 4
    for (int d = 0; d < D; ++d) {
      float q = Qc[d * D];
#pragma unroll
      for (int s4 = 0; s4 < SB / 4; ++s4) {
        float4 v = *(const float4*)&Y[d][s4 * 4];
        z[s4 * 4 + 0] += q * v.x;
        z[s4 * 4 + 1] += q * v.y;
        z[s4 * 4 + 2] += q * v.z;
        z[s4 * 4 + 3] += q * v.w;
      }
    }
  }

  // score[s] = sum_k y*z : block tree-reduction (reuse V)
#pragma unroll
  for (int s = 0; s < SB; ++s) V[t][s] = y[s] * z[s];
  __syncthreads();
  for (int st = 64; st >= 1; st >>= 1) {
    if (t < st) {
#pragma unroll
      for (int s = 0; s < SB; ++s) V[t][s] += V[t + st][s];
    }
    __syncthreads();
  }
  if (t < SB) sc[n0 + t] = V[0][t];

  // hi/lo split into LDS transpose buffers (enroll rows carry 2*lam)
  const float scale = mode ? 1.0f : 2.0f * lam[t];
#pragma unroll
  for (int s = 0; s < SB; ++s) {
    float w = y[s] * scale;
    unsigned short hi = f32_to_bf16(w);
    unsigned short lo = f32_to_bf16(w - bf16_to_f32(hi));
    H[s][t] = hi;
    L[s][t] = lo;
  }
  __syncthreads();

  // packed writeout: 768 chunks of 16B; sections: [H, mode?L:H, mode?H:L]
  uint4* outc = (uint4*)Ext + (size_t)R * 768;
#pragma unroll
  for (int i = 0; i < 6; ++i) {
    const int c = i * 128 + t;
    const int kb = c >> 6;          // wave-uniform
    const int sec = kb >> 2;
    const int koct = (c >> 4) & 3;
    const int s = c & 15;
    const int kin = ((kb & 3) << 5) | (koct << 3);
    const unsigned short* src;
    if (sec == 0)      src = &H[s][kin];
    else if (sec == 1) src = mode ? &L[s][kin] : &H[s][kin];
    else               src = mode ? &H[s][kin] : &L[s][kin];
    outc[c] = *(const uint4*)src;
  }
}

// ---------------------------------------------------------------- main GEMM: no LDS,
// fragments loaded direct from packed global, register double-buffered.
// C[n][m] = sum_kext A[n][.]*B[m][.] + s1[n] + s2[m]
__global__ __launch_bounds__(256) void gemm_score(
    const unsigned short* __restrict__ A,  // packed [512][12][512] u16
    const unsigned short* __restrict__ B,
    const float* __restrict__ s1, const float* __restrict__ s2,
    float* __restrict__ C) {
  // XCD-aware chunked swizzle: xcd = bid&7 owns by in [xcd*8, xcd*8+8),
  // column-major within chunk (8 consecutive q share one B panel; A set stays L2-resident)
  const int bid = blockIdx.x;          // 0..4095
  const int xcd = bid & 7;
  const int q = bid >> 3;              // 0..511
  const int bx = q >> 3;               // 0..63  (test / N)
  const int by = (xcd << 3) | (q & 7); // 0..63  (enroll / M)
  const int bm0 = by * 128;
  const int bn0 = bx * 128;

  const int t = threadIdx.x;
  const int l = t & 63;
  const int w = t >> 6;
  const int wr = w >> 1;
  const int wc = w & 1;

  f32x4 acc[4][4];
  const f32x4 zero = {0.f, 0.f, 0.f, 0.f};
#pragma unroll
  for (int m = 0; m < 4; ++m)
#pragma unroll
    for (int n = 0; n < 4; ++n) acc[m][n] = zero;

  // lane base pointers into packed layout (u16 units)
  const unsigned short* pa = A + ((size_t)((bm0 >> 4) + wr * 4) * NKB) * 512 + l * 8;
  const unsigned short* pb = B + ((size_t)((bn0 >> 4) + wc * 4) * NKB) * 512 + l * 8;
  // fragment (m, kt) at pa + m*(NKB*512) + kt*512

  bf16x8 af[2][4], bf[2][4];
#pragma unroll
  for (int m = 0; m < 4; ++m) {
    af[0][m] = *(const bf16x8*)(pa + m * (NKB * 512));
    bf[0][m] = *(const bf16x8*)(pb + m * (NKB * 512));
  }

#pragma unroll
  for (int kt = 0; kt < NKB; ++kt) {
    const int cur = kt & 1, nxt = cur ^ 1;
    if (kt < NKB - 1) {
#pragma unroll
      for (int m = 0; m < 4; ++m) {
        af[nxt][m] = *(const bf16x8*)(pa + m * (NKB * 512) + (kt + 1) * 512);
        bf[nxt][m] = *(const bf16x8*)(pb + m * (NKB * 512) + (kt + 1) * 512);
      }
    }
#pragma unroll
    for (int m = 0; m < 4; ++m)
#pragma unroll
      for (int n = 0; n < 4; ++n)
        acc[m][n] =
            __builtin_amdgcn_mfma_f32_16x16x32_bf16(af[cur][m], bf[cur][n], acc[m][n], 0, 0, 0);
  }

  // epilogue: + s1[row] + s2[col]
  const int rr = l & 15;
  const int rq = l >> 4;
  float s2v[4];
#pragma unroll
  for (int n = 0; n < 4; ++n) s2v[n] = s2[bn0 + wc * 64 + n * 16 + rr];
#pragma unroll
  for (int m = 0; m < 4; ++m) {
#pragma unroll
    for (int r = 0; r < 4; ++r) {
      const int row = bm0 + wr * 64 + m * 16 + rq * 4 + r;
      const float s1v = s1[row];
      float* cp = C + (size_t)row * NT + bn0 + wc * 64 + rr;
#pragma unroll
      for (int n = 0; n < 4; ++n) cp[n * 16] = acc[m][n][r] + s1v + s2v[n];
    }
  }
}

// ----------------------------------------------------------------
extern "C" void kernel_launch(void* const* d_in, const int* in_sizes, int n_in,
                              void* d_out, int out_size, void* d_ws, size_t ws_size,
                              hipStream_t stream) {
  const float* x_enroll = (const float*)d_in[0];
  const float* x_test   = (const float*)d_in[1];
  const float* W        = (const float*)d_in[2];
  const float* miu      = (const float*)d_in[3];
  const float* lam      = (const float*)d_in[4];
  const float* U_k      = (const float*)d_in[5];
  const float* Q_hat    = (const float*)d_in[6];
  float* out = (float*)d_out;

  char* ws = (char*)d_ws;
  float* M  = (float*)ws;                       // 64 KB
  float* s1 = (float*)(ws + 65536);             // 32 KB
  float* s2 = (float*)(ws + 98304);             // 32 KB
  unsigned short* Aext = (unsigned short*)(ws + 131072);             // 6 MB packed
  unsigned short* Bext = (unsigned short*)(ws + 131072 + 6291456);   // 6 MB packed

  prep_M<<<dim3(D), dim3(D), 0, stream>>>(W, U_k, M);
  project_kernel<<<dim3(NE / SB, 2), dim3(128), 0, stream>>>(
      x_enroll, x_test, miu, M, Q_hat, lam, Aext, Bext, s1, s2);
  gemm_score<<<dim3(4096), dim3(256), 0, stream>>>(Aext, Bext, s1, s2, out);
}

// Round 3
// 342.027 us; speedup vs baseline: 1.0864x; 1.0864x over previous
//
#include <hip/hip_runtime.h>
#include <math.h>

#define D 128
#define NE 8192
#define NT 8192
#define KEXT 384         // [Ah|Ah|Al] x [Bh|Bl|Bh] -> Ah.Bh + Ah.Bl + Al.Bh
#define NKB (KEXT / 32)  // 12 k-blocks of 32
#define SB 16            // samples per projection block (= one 16-row fragment tile)

typedef __bf16 bf16x8 __attribute__((ext_vector_type(8)));
typedef float f32x4 __attribute__((ext_vector_type(4)));

__device__ __forceinline__ unsigned short f32_to_bf16(float f) {
  unsigned int u = __float_as_uint(f);
  u += 0x7FFFu + ((u >> 16) & 1u);   // RNE
  return (unsigned short)(u >> 16);
}
__device__ __forceinline__ float bf16_to_f32(unsigned short h) {
  return __uint_as_float(((unsigned int)h) << 16);
}

#define GLOAD_LDS16(g, l)                                                      \
  __builtin_amdgcn_global_load_lds(                                            \
      (__attribute__((address_space(1))) const void*)(g),                      \
      (__attribute__((address_space(3))) void*)(l), 16, 0, 0)

// ---------------------------------------------------------------- prep: M = W @ U_k
__global__ __launch_bounds__(128) void prep_M(const float* __restrict__ W,
                                              const float* __restrict__ U,
                                              float* __restrict__ M) {
  const int d = blockIdx.x;
  const int k = threadIdx.x;
  const float* Wr = W + d * D;
  float acc = 0.f;
#pragma unroll 8
  for (int c = 0; c < D; ++c) acc += Wr[c] * U[c * D + k];
  M[d * D + k] = acc;  // y[k] = sum_d M[d][k] v[d]
}

// ---------------------------------------------------------------- projection + scores
// Emits A/B in MFMA-fragment-packed layout:
//   chunk index (uint4 units) = rowblk*768 + kb*64 + koct*16 + s
//   GEMM lane l reads chunk (koct = l>>4, s = l&15) of (rowblk, kb).
__global__ __launch_bounds__(128) void project_kernel(
    const float* __restrict__ Xe, const float* __restrict__ Xt,
    const float* __restrict__ miu, const float* __restrict__ M,
    const float* __restrict__ Qh, const float* __restrict__ lam,
    unsigned short* __restrict__ Aext, unsigned short* __restrict__ Bext,
    float* __restrict__ s1, float* __restrict__ s2) {
  const int t = threadIdx.x;          // t = dim d (load) / output k (matvecs)
  const int mode = blockIdx.y;        // 0 = enroll, 1 = test
  const int R = blockIdx.x;           // rowblk
  const int n0 = R * SB;
  const float* X = mode ? Xt : Xe;
  unsigned short* Ext = mode ? Bext : Aext;
  float* sc = mode ? s2 : s1;

  __shared__ __align__(16) float V[D][20];
  __shared__ __align__(16) float Y[D][20];
  __shared__ float rn[SB];
  __shared__ __align__(16) unsigned short H[SB][136];  // pad 136: conflict-free col reads
  __shared__ __align__(16) unsigned short L[SB][136];

  // load + center
  const float mu = miu[t];
#pragma unroll
  for (int i = 0; i < SB; ++i)
    V[t][i] = X[(size_t)(n0 + i) * D + t] - mu;
  __syncthreads();

  // per-sample inverse norm
  if (t < SB) {
    float s = 0.f;
#pragma unroll 8
    for (int d = 0; d < D; ++d) { float v = V[d][t]; s += v * v; }
    rn[t] = 1.0f / (sqrtf(s) + 1e-8f);
  }
  __syncthreads();

  // matvec1: y[k=t][s] = sum_d M[d][k] * V[d][s]
  float y[SB];
#pragma unroll
  for (int s = 0; s < SB; ++s) y[s] = 0.f;
  {
    const float* Mc = M + t;
#pragma unroll 4
    for (int d = 0; d < D; ++d) {
      float m = Mc[d * D];
#pragma unroll
      for (int s4 = 0; s4 < SB / 4; ++s4) {
        float4 v = *(const float4*)&V[d][s4 * 4];
        y[s4 * 4 + 0] += m * v.x;
        y[s4 * 4 + 1] += m * v.y;
        y[s4 * 4 + 2] += m * v.z;
        y[s4 * 4 + 3] += m * v.w;
      }
    }
  }
#pragma unroll
  for (int s = 0; s < SB; ++s) y[s] *= rn[s];

#pragma unroll
  for (int s4 = 0; s4 < SB / 4; ++s4) {
    float4 v;
    v.x = y[s4 * 4 + 0]; v.y = y[s4 * 4 + 1];
    v.z = y[s4 * 4 + 2]; v.w = y[s4 * 4 + 3];
    *(float4*)&Y[t][s4 * 4] = v;
  }
  __syncthreads();

  // matvec2: z[k=t][s] = sum_d Qh[d][k] * Y[d][s]  (Q_hat symmetric)
  float z[SB];
#pragma unroll
  for (int s = 0; s < SB; ++s) z[s] = 0.f;
  {
    const float* Qc = Qh + t;
#pragma unroll 4
    for (int d = 0; d < D; ++d) {
      float q = Qc[d * D];
#pragma unroll
      for (int s4 = 0; s4 < SB / 4; ++s4) {
        float4 v = *(const float4*)&Y[d][s4 * 4];
        z[s4 * 4 + 0] += q * v.x;
        z[s4 * 4 + 1] += q * v.y;
        z[s4 * 4 + 2] += q * v.z;
        z[s4 * 4 + 3] += q * v.w;
      }
    }
  }

  // score[s] = sum_k y*z : block tree-reduction (reuse V)
#pragma unroll
  for (int s = 0; s < SB; ++s) V[t][s] = y[s] * z[s];
  __syncthreads();
  for (int st = 64; st >= 1; st >>= 1) {
    if (t < st) {
#pragma unroll
      for (int s = 0; s < SB; ++s) V[t][s] += V[t + st][s];
    }
    __syncthreads();
  }
  if (t < SB) sc[n0 + t] = V[0][t];

  // hi/lo split into LDS transpose buffers (enroll rows carry 2*lam)
  const float scale = mode ? 1.0f : 2.0f * lam[t];
#pragma unroll
  for (int s = 0; s < SB; ++s) {
    float w = y[s] * scale;
    unsigned short hi = f32_to_bf16(w);
    unsigned short lo = f32_to_bf16(w - bf16_to_f32(hi));
    H[s][t] = hi;
    L[s][t] = lo;
  }
  __syncthreads();

  // packed writeout: 768 chunks of 16B; sections: [H, mode?L:H, mode?H:L]
  uint4* outc = (uint4*)Ext + (size_t)R * 768;
#pragma unroll
  for (int i = 0; i < 6; ++i) {
    const int c = i * 128 + t;
    const int kb = c >> 6;          // wave-uniform
    const int sec = kb >> 2;
    const int koct = (c >> 4) & 3;
    const int s = c & 15;
    const int kin = ((kb & 3) << 5) | (koct << 3);
    const unsigned short* src;
    if (sec == 0)      src = &H[s][kin];
    else if (sec == 1) src = mode ? &L[s][kin] : &H[s][kin];
    else               src = mode ? &H[s][kin] : &L[s][kin];
    outc[c] = *(const uint4*)src;
  }
}

// ---------------------------------------------------------------- main GEMM:
// m97 structure over packed-fragment layout. LDS staged via global_load_lds
// (zero staging VGPRs), conflict-free linear fragment reads, 1 barrier/kt.
// C[n][m] = sum_kext A[n][.]*B[m][.] + s1[n] + s2[m]
__global__ __launch_bounds__(256) void gemm_score(
    const unsigned short* __restrict__ A,  // packed [512][12][512] u16
    const unsigned short* __restrict__ B,
    const float* __restrict__ s1, const float* __restrict__ s2,
    float* __restrict__ C) {
  // LDS: [buf][ A: 8 groups x 512 | B: 8 groups x 512 ] u16  (32 KB total)
  __shared__ __align__(16) unsigned short S[2][8192];

  // XCD-aware chunked swizzle: 8 consecutive blocks on one XCD share a B panel,
  // A chunk (8 panels) stays L2-resident across the bx sweep.
  const int bid = blockIdx.x;          // 0..4095
  const int xcd = bid & 7;
  const int q = bid >> 3;              // 0..511
  const int bx = q >> 3;               // 0..63  (test / N)
  const int by = (xcd << 3) | (q & 7); // 0..63  (enroll / M)
  const int bm0 = by * 128;
  const int bn0 = bx * 128;

  const int t = threadIdx.x;
  const int l = t & 63;
  const int w = t >> 6;     // wave 0..3
  const int wr = w >> 1;
  const int wc = w & 1;

  // staging assignment: wave w stages groups gid = 4w..4w+3.
  // gid<8: A rowblk gid ; gid>=8: B rowblk gid-8.
  const unsigned short* srcp[4];
  int dsto[4];
#pragma unroll
  for (int j = 0; j < 4; ++j) {
    const int gid = w * 4 + j;
    const int rb = gid & 7;
    const unsigned short* base = (gid < 8) ? A : B;
    const int t0 = (gid < 8) ? bm0 : bn0;
    srcp[j] = base + ((size_t)((t0 >> 4) + rb) * NKB) * 512 + l * 8;
    dsto[j] = ((gid < 8) ? 0 : 4096) + rb * 512 + l * 8;
  }

  f32x4 acc[4][4];
  const f32x4 zero = {0.f, 0.f, 0.f, 0.f};
#pragma unroll
  for (int m = 0; m < 4; ++m)
#pragma unroll
    for (int n = 0; n < 4; ++n) acc[m][n] = zero;

  // prologue: stage kt=0 into buf 0
#pragma unroll
  for (int j = 0; j < 4; ++j) GLOAD_LDS16(srcp[j], &S[0][dsto[j]]);
  __syncthreads();

#pragma unroll
  for (int kt = 0; kt < NKB; ++kt) {
    const int buf = kt & 1;
    if (kt + 1 < NKB) {
#pragma unroll
      for (int j = 0; j < 4; ++j)
        GLOAD_LDS16(srcp[j] + (kt + 1) * 512, &S[buf ^ 1][dsto[j]]);
    }
    bf16x8 af[4], bfv[4];
#pragma unroll
    for (int m = 0; m < 4; ++m)
      af[m] = *(const bf16x8*)&S[buf][(wr * 4 + m) * 512 + l * 8];
#pragma unroll
    for (int n = 0; n < 4; ++n)
      bfv[n] = *(const bf16x8*)&S[buf][4096 + (wc * 4 + n) * 512 + l * 8];
#pragma unroll
    for (int m = 0; m < 4; ++m)
#pragma unroll
      for (int n = 0; n < 4; ++n)
        acc[m][n] =
            __builtin_amdgcn_mfma_f32_16x16x32_bf16(af[m], bfv[n], acc[m][n], 0, 0, 0);
    __syncthreads();  // drains vmcnt: next buf staged; all reads of cur done
  }

  // epilogue: + s1[row] + s2[col]
  const int rr = l & 15;
  const int rq = l >> 4;
  float s2v[4];
#pragma unroll
  for (int n = 0; n < 4; ++n) s2v[n] = s2[bn0 + wc * 64 + n * 16 + rr];
#pragma unroll
  for (int m = 0; m < 4; ++m) {
#pragma unroll
    for (int r = 0; r < 4; ++r) {
      const int row = bm0 + wr * 64 + m * 16 + rq * 4 + r;
      const float s1v = s1[row];
      float* cp = C + (size_t)row * NT + bn0 + wc * 64 + rr;
#pragma unroll
      for (int n = 0; n < 4; ++n) cp[n * 16] = acc[m][n][r] + s1v + s2v[n];
    }
  }
}

// ----------------------------------------------------------------
extern "C" void kernel_launch(void* const* d_in, const int* in_sizes, int n_in,
                              void* d_out, int out_size, void* d_ws, size_t ws_size,
                              hipStream_t stream) {
  const float* x_enroll = (const float*)d_in[0];
  const float* x_test   = (const float*)d_in[1];
  const float* W        = (const float*)d_in[2];
  const float* miu      = (const float*)d_in[3];
  const float* lam      = (const float*)d_in[4];
  const float* U_k      = (const float*)d_in[5];
  const float* Q_hat    = (const float*)d_in[6];
  float* out = (float*)d_out;

  char* ws = (char*)d_ws;
  float* M  = (float*)ws;                       // 64 KB
  float* s1 = (float*)(ws + 65536);             // 32 KB
  float* s2 = (float*)(ws + 98304);             // 32 KB
  unsigned short* Aext = (unsigned short*)(ws + 131072);             // 6 MB packed
  unsigned short* Bext = (unsigned short*)(ws + 131072 + 6291456);   // 6 MB packed

  prep_M<<<dim3(D), dim3(D), 0, stream>>>(W, U_k, M);
  project_kernel<<<dim3(NE / SB, 2), dim3(128), 0, stream>>>(
      x_enroll, x_test, miu, M, Q_hat, lam, Aext, Bext, s1, s2);
  gemm_score<<<dim3(4096), dim3(256), 0, stream>>>(Aext, Bext, s1, s2, out);
}